// Round 10
// baseline (1932.435 us; speedup 1.0000x reference)
//
#include <hip/hip_runtime.h>
#include <math.h>
#include <stdint.h>

#define B_TOT 2048
#define SEQ   512
#define DIN   5
#define HID   64
#define EDIM  32
#define NEMB  64
#define BT    8
#define NBLK_STREAM 256
#define COMB  96
#define OUTC  (B_TOT*COMB)

typedef __attribute__((ext_vector_type(8))) _Float16 half8;  // 8 fp16 = 4 VGPRs
typedef __attribute__((ext_vector_type(4))) float float4v;

__device__ __forceinline__ float fsig(float x){ return 1.0f/(1.0f + __expf(-x)); }
__device__ __forceinline__ float ftanh(float x){
  float xc = fminf(fmaxf(x, -15.f), 15.f);
  float e  = __expf(-2.f*xc);
  return (1.f - e) / (1.f + e);
}
#define MFMA16(a,b,c) __builtin_amdgcn_mfma_f32_16x16x32_f16((a),(b),(c),0,0,0)

// Fused dual-stream, fp16. 512 blocks x 1024 thr -> 2 blocks/CU (32 waves/CU)
// so the two blocks' barrier phases overlap. blocks [0,256)=CNN, [256,512)=VQ,
// BT=8 batches/block (B cols 8..15 zero pad). Per-thread weight regs = 28
// (the spill-free shape: R8 proven; R9's 56-reg shape spilled to scratch).
// LDS operand = 5 shared K-tiles: T0=Y/x, T1=h0[0:32), T2=h0[32:64),
// T3=h1[0:32), T4=h1[32:64). L0 reads {T0,T1,T2}; L1 reads {T1,T2,T3,T4}.
// Wave w owns M-tile w, PERMUTED rows (tile row m <-> orig row
// 64*(m&3)+4*w+(m>>2)) so D reg r = gate r of unit u=4w+quad -> act fully
// in-register; bias pre-loaded as the MFMA C operand. 2 barriers/step.
__global__ __launch_bounds__(1024)
__attribute__((amdgpu_waves_per_eu(8, 8)))
void fused_kernel(const float* __restrict__ xg,
                  const float* __restrict__ conv_w, const float* __restrict__ conv_b,
                  const float* __restrict__ bn_g, const float* __restrict__ bn_b,
                  const float* __restrict__ bn_m, const float* __restrict__ bn_v,
                  const float* __restrict__ cnn0_wih, const float* __restrict__ cnn0_whh,
                  const float* __restrict__ cnn0_bih, const float* __restrict__ cnn0_bhh,
                  const float* __restrict__ cnn1_wih, const float* __restrict__ cnn1_whh,
                  const float* __restrict__ cnn1_bih, const float* __restrict__ cnn1_bhh,
                  const float* __restrict__ vq0_wih, const float* __restrict__ vq0_whh,
                  const float* __restrict__ vq0_bih, const float* __restrict__ vq0_bhh,
                  const float* __restrict__ vq1_wih, const float* __restrict__ vq1_whh,
                  const float* __restrict__ vq1_bih, const float* __restrict__ vq1_bhh,
                  const float* __restrict__ proj_w, const float* __restrict__ proj_b,
                  const float* __restrict__ codebook,
                  float* __restrict__ out, float* __restrict__ ws_f,
                  int* __restrict__ ws_hist)
{
  __shared__ __align__(16) _Float16 ZT[5][4][16][8];   // 5 K-tiles, 16 cols (8 pad)
  __shared__ __align__(16) float hfin[BT][HID];
  __shared__ __align__(16) float pbuf[BT][EDIM];
  __shared__ float wcs[16][32];
  __shared__ float xwin[3][BT][DIN];

  const int tid  = threadIdx.x;
  const bool is_cnn = (blockIdx.x < NBLK_STREAM);
  const int b0   = (is_cnn ? blockIdx.x : blockIdx.x - NBLK_STREAM) * BT;
  const int w    = tid >> 6;      // wave = M-tile, 0..15
  const int lane = tid & 63;
  const int n16  = lane & 15;     // B/D col; batch if < 8
  const int quad = lane >> 4;
  const int u    = 4*w + quad;    // unit owned by this lane
  const bool act_lane = (n16 < BT);

  const float* wih0 = is_cnn ? cnn0_wih : vq0_wih;
  const float* whh0 = is_cnn ? cnn0_whh : vq0_whh;
  const float* bih0 = is_cnn ? cnn0_bih : vq0_bih;
  const float* bhh0 = is_cnn ? cnn0_bhh : vq0_bhh;
  const float* wih1 = is_cnn ? cnn1_wih : vq1_wih;
  const float* whh1 = is_cnn ? cnn1_whh : vq1_whh;
  const float* bih1 = is_cnn ? cnn1_bih : vq1_bih;
  const float* bhh1 = is_cnn ? cnn1_bhh : vq1_bhh;

  // ---- A-frags fp16, permuted rows. A[m=lane&15][k=quad*8+j]. 28 VGPRs.
  const int orow = 64*(n16 & 3) + 4*w + (n16 >> 2);
  half8 Ah0[3], Ah1[4];
#pragma unroll
  for (int kt = 0; kt < 3; ++kt) {
    half8 vh;
#pragma unroll
    for (int j = 0; j < 8; ++j) {
      const int g = kt*32 + quad*8 + j;
      float wv;
      if (is_cnn) wv = (g < 32) ? wih0[orow*32 + g] : whh0[orow*64 + (g-32)];
      else        wv = (g < 5) ? wih0[orow*5 + g] : (g < 32 ? 0.f : whh0[orow*64 + (g-32)]);
      vh[j] = (_Float16)wv;
    }
    Ah0[kt] = vh;
  }
#pragma unroll
  for (int kt = 0; kt < 4; ++kt) {
    half8 vh;
#pragma unroll
    for (int j = 0; j < 8; ++j) {
      const int g = kt*32 + quad*8 + j;
      float wv = (g < 64) ? wih1[orow*64 + g] : whh1[orow*64 + (g-64)];
      vh[j] = (_Float16)wv;
    }
    Ah1[kt] = vh;
  }

  // biases as MFMA C-init: reg r = gate r of unit u
  float4v bc0, bc1;
#pragma unroll
  for (int r = 0; r < 4; ++r) {
    bc0[r] = bih0[64*r + u] + bhh0[64*r + u];
    bc1[r] = bih1[64*r + u] + bhh1[64*r + u];
  }

  // zero ZT (pads + h(-1)=0): 5*4*16*8 halfwords = 1280 u32
  for (int i2 = tid; i2 < 5*4*16*8/2; i2 += 1024) ((uint32_t*)ZT)[i2] = 0;

  const int xn = tid / 5, xi = tid % 5;
  float xpref = 0.f;

  _Float16* Zb = (_Float16*)ZT;
  #define ZIDX(tile,k32,n) (((tile)*4 + (((k32)>>3)&3))*128 + (n)*8 + ((k32)&7))

  // ================= prologue =================
  if (is_cnn) {
    if (tid < 32) {
      float s = bn_g[tid] * rsqrtf(bn_v[tid] + 1e-5f);
#pragma unroll
      for (int i = 0; i < 5; ++i)
#pragma unroll
        for (int tau = 0; tau < 3; ++tau)
          wcs[tau*5 + i][tid] = conv_w[tid*15 + i*3 + tau] * s;
      wcs[15][tid] = (conv_b[tid] - bn_m[tid]) * s + bn_b[tid];
    }
    if (tid < BT*DIN) {
      xwin[0][xn][xi] = xg[((size_t)(b0+xn)*SEQ + 0)*DIN + xi];
      xwin[1][xn][xi] = xg[((size_t)(b0+xn)*SEQ + 1)*DIN + xi];
      xwin[2][xn][xi] = xg[((size_t)(b0+xn)*SEQ + 2)*DIN + xi];
    }
    __syncthreads();
    if (tid < 256) {   // conv y(0): taps x(-1)=0, x(0), x(1) -> T0
      const int cc = tid >> 3, cn = tid & 7;
      float s = wcs[15][cc];
#pragma unroll
      for (int i = 0; i < 5; ++i)
        s += wcs[5+i][cc]*xwin[0][cn][i] + wcs[10+i][cc]*xwin[1][cn][i];
      s = fmaxf(s, 0.f);
      Zb[ZIDX(0, cc, cn)] = (_Float16)s;
    }
  } else {
    if (tid < BT*DIN) {   // x(0) -> T0 k<5
      float xv = xg[((size_t)(b0+xn)*SEQ + 0)*DIN + xi];
      Zb[ZIDX(0, xi, xn)] = (_Float16)xv;
    }
  }
  __syncthreads();

  float c0 = 0.f, c1 = 0.f, h1v = 0.f;
  // MFMA G0(0)
  {
    half8 bt0 = *(const half8*)&ZT[0][quad][n16][0];
    half8 bt1 = *(const half8*)&ZT[1][quad][n16][0];
    half8 bt2 = *(const half8*)&ZT[2][quad][n16][0];
    float4v a0 = bc0;
    a0 = MFMA16(Ah0[0], bt0, a0);
    a0 = MFMA16(Ah0[1], bt1, a0);
    a0 = MFMA16(Ah0[2], bt2, a0);
    __syncthreads();   // reads done before act writes
    if (act_lane) {
      c0 = fsig(a0[1])*c0 + fsig(a0[0])*ftanh(a0[2]);
      float h0 = fsig(a0[3])*ftanh(c0);
      Zb[ZIDX(1 + (u>>5), u & 31, n16)] = (_Float16)h0;
    }
  }
  // stage y(1)/x(1), prefetch
  if (is_cnn) {
    if (tid < 256) {   // conv y(1): x(0),x(1),x(2)
      const int cc = tid >> 3, cn = tid & 7;
      float s = wcs[15][cc];
#pragma unroll
      for (int i = 0; i < 5; ++i)
        s += wcs[i][cc]*xwin[0][cn][i] + wcs[5+i][cc]*xwin[1][cn][i]
           + wcs[10+i][cc]*xwin[2][cn][i];
      s = fmaxf(s, 0.f);
      Zb[ZIDX(0, cc, cn)] = (_Float16)s;
    }
    if (tid < BT*DIN) xpref = xg[((size_t)(b0+xn)*SEQ + 3)*DIN + xi];   // x(3)
  } else {
    if (tid < BT*DIN) {    // x(1) -> T0
      float xv = xg[((size_t)(b0+xn)*SEQ + 1)*DIN + xi];
      Zb[ZIDX(0, xi, xn)] = (_Float16)xv;
      xpref = xg[((size_t)(b0+xn)*SEQ + 2)*DIN + xi];                   // x(2)
    }
  }
  __syncthreads();

  int sp = 1, scu = 2, snx = 0;   // cnn xwin slots: x(t+1), x(t+2), x(t+3)-incoming

  // ================= main loop: 2 barriers/step =================
  for (int t = 0; t < SEQ; ++t) {
    // ---- phase A: commit x(t+3) (cnn) + MFMA G1(t), G0(t+1)
    if (is_cnn && tid < BT*DIN) xwin[snx][xn][xi] = xpref;
    half8 bt0 = *(const half8*)&ZT[0][quad][n16][0];
    half8 bt1 = *(const half8*)&ZT[1][quad][n16][0];
    half8 bt2 = *(const half8*)&ZT[2][quad][n16][0];
    half8 bt3 = *(const half8*)&ZT[3][quad][n16][0];
    half8 bt4 = *(const half8*)&ZT[4][quad][n16][0];
    float4v a1 = bc1, a0 = bc0;
    a1 = MFMA16(Ah1[0], bt1, a1);
    a1 = MFMA16(Ah1[1], bt2, a1);
    a1 = MFMA16(Ah1[2], bt3, a1);
    a1 = MFMA16(Ah1[3], bt4, a1);
    a0 = MFMA16(Ah0[0], bt0, a0);
    a0 = MFMA16(Ah0[1], bt1, a0);
    a0 = MFMA16(Ah0[2], bt2, a0);
    __syncthreads();  // A -> B (all Z reads complete)

    // ---- phase B: in-register acts + Z writes + conv/x staging
    if (act_lane) {
      {  // L1 act(t)
        c1 = fsig(a1[1])*c1 + fsig(a1[0])*ftanh(a1[2]);
        float h1 = fsig(a1[3])*ftanh(c1);
        Zb[ZIDX(3 + (u>>5), u & 31, n16)] = (_Float16)h1;
        if (is_cnn) h1v = h1;
        else if (t == SEQ-1) hfin[n16][u] = h1;
      }
      {  // L0 act(t+1)
        c0 = fsig(a0[1])*c0 + fsig(a0[0])*ftanh(a0[2]);
        float h0 = fsig(a0[3])*ftanh(c0);
        Zb[ZIDX(1 + (u>>5), u & 31, n16)] = (_Float16)h0;
      }
    }
    if (is_cnn) {      // conv y(t+2): x(t+1),x(t+2),x(t+3)
      if (tid < 256) {
        const int cc = tid >> 3, cn = tid & 7;
        float s = wcs[15][cc];
#pragma unroll
        for (int i = 0; i < 5; ++i)
          s += wcs[i][cc]*xwin[sp][cn][i] + wcs[5+i][cc]*xwin[scu][cn][i]
             + wcs[10+i][cc]*xwin[snx][cn][i];
        s = fmaxf(s, 0.f);
        Zb[ZIDX(0, cc, cn)] = (_Float16)s;
      }
      if (tid < BT*DIN) {
        const int tq = t + 4;
        xpref = (tq < SEQ) ? xg[((size_t)(b0+xn)*SEQ + tq)*DIN + xi] : 0.f;
      }
    } else {
      if (tid < BT*DIN) {  // x(t+2) -> T0
        Zb[ZIDX(0, xi, xn)] = (_Float16)xpref;
        const int tq = t + 3;
        xpref = (tq < SEQ) ? xg[((size_t)(b0+xn)*SEQ + tq)*DIN + xi] : 0.f;
      }
    }
    { int tmp = sp; sp = scu; scu = snx; snx = tmp; }
    __syncthreads();  // B -> A(t+1)
  }

  // ================= epilogue =================
  if (is_cnn) {
    if (act_lane) {
      const size_t gb = (size_t)(b0 + n16);
      out[gb*COMB + u]        = h1v;
      out[OUTC + gb*COMB + u] = h1v;
    }
  } else {
    if (tid < 256) {  // projection: vq_proj[8][32]
      const int pn = tid >> 5, pe = tid & 31;
      float s = proj_b[pe];
      const float* pw = proj_w + pe*HID;
#pragma unroll
      for (int k = 0; k < HID; ++k) s += hfin[pn][k] * pw[k];
      pbuf[pn][pe] = s;
    }
    __syncthreads();
    // argmin: wave w handles batch w (w<8), lane = code idx
    if (w < BT) {
      const int bb = w;
      const int nn = lane;
      const float* cbn = codebook + nn*EDIM;
      float d = 0.f;
#pragma unroll
      for (int k = 0; k < EDIM; ++k) { float df = pbuf[bb][k] - cbn[k]; d += df*df; }
      int bi = nn;
#pragma unroll
      for (int off = 32; off > 0; off >>= 1) {
        float od = __shfl_down(d, off, 64);
        int   oi = __shfl_down(bi, off, 64);
        if (od < d || (od == d && oi < bi)) { d = od; bi = oi; }
      }
      bi = __shfl(bi, 0, 64);
      float lv = 0.f;
      if (nn < EDIM) {
        float q = codebook[bi*EDIM + nn];
        const size_t gb = (size_t)(b0 + bb);
        out[gb*COMB + HID + nn]        = q;
        out[OUTC + gb*COMB + HID + nn] = q;
        float df = q - pbuf[bb][nn];
        lv = df*df;
      }
#pragma unroll
      for (int off = 32; off > 0; off >>= 1) lv += __shfl_down(lv, off, 64);
      if (nn == 0) { atomicAdd(ws_f, lv); atomicAdd(&ws_hist[bi], 1); }
    }
  }
}

// ===================== scalars =====================
__global__ void zero_ws_kernel(float* ws_f, int* ws_hist) {
  const int t = threadIdx.x;
  if (t == 0) ws_f[0] = 0.f;
  if (t < NEMB) ws_hist[t] = 0;
}

__global__ void vq_finalize_kernel(const float* __restrict__ ws_f,
                                   const int* __restrict__ ws_hist,
                                   float* __restrict__ out) {
  const int t = threadIdx.x;  // 64 threads = 1 wave
  float p = (float)ws_hist[t] * (1.0f / (float)B_TOT);
  float e = -p * logf(p + 1e-10f);
#pragma unroll
  for (int off = 32; off > 0; off >>= 1) e += __shfl_down(e, off, 64);
  if (t == 0) {
    float mse = ws_f[0] * (1.0f / (float)(B_TOT * EDIM));
    out[2*OUTC + 0] = mse * 1.01f;   // q_loss + 0.01*e_loss (identical fwd)
    out[2*OUTC + 1] = expf(e);       // perplexity
  }
}

extern "C" void kernel_launch(void* const* d_in, const int* in_sizes, int n_in,
                              void* d_out, int out_size, void* d_ws, size_t ws_size,
                              hipStream_t stream) {
  const float* x        = (const float*)d_in[0];
  const float* conv_w   = (const float*)d_in[1];
  const float* conv_b   = (const float*)d_in[2];
  const float* bn_g     = (const float*)d_in[3];
  const float* bn_b     = (const float*)d_in[4];
  const float* bn_m     = (const float*)d_in[5];
  const float* bn_v     = (const float*)d_in[6];
  const float* cnn0_wih = (const float*)d_in[7];
  const float* cnn0_whh = (const float*)d_in[8];
  const float* cnn0_bih = (const float*)d_in[9];
  const float* cnn0_bhh = (const float*)d_in[10];
  const float* cnn1_wih = (const float*)d_in[11];
  const float* cnn1_whh = (const float*)d_in[12];
  const float* cnn1_bih = (const float*)d_in[13];
  const float* cnn1_bhh = (const float*)d_in[14];
  const float* vq0_wih  = (const float*)d_in[15];
  const float* vq0_whh  = (const float*)d_in[16];
  const float* vq0_bih  = (const float*)d_in[17];
  const float* vq0_bhh  = (const float*)d_in[18];
  const float* vq1_wih  = (const float*)d_in[19];
  const float* vq1_whh  = (const float*)d_in[20];
  const float* vq1_bih  = (const float*)d_in[21];
  const float* vq1_bhh  = (const float*)d_in[22];
  const float* proj_w   = (const float*)d_in[23];
  const float* proj_b   = (const float*)d_in[24];
  const float* codebook = (const float*)d_in[25];

  float* out     = (float*)d_out;
  float* ws_f    = (float*)d_ws;
  int*   ws_hist = (int*)d_ws + 16;

  hipLaunchKernelGGL(zero_ws_kernel, dim3(1), dim3(64), 0, stream, ws_f, ws_hist);
  hipLaunchKernelGGL(fused_kernel, dim3(2*NBLK_STREAM), dim3(1024), 0, stream,
                     x, conv_w, conv_b, bn_g, bn_b, bn_m, bn_v,
                     cnn0_wih, cnn0_whh, cnn0_bih, cnn0_bhh,
                     cnn1_wih, cnn1_whh, cnn1_bih, cnn1_bhh,
                     vq0_wih, vq0_whh, vq0_bih, vq0_bhh,
                     vq1_wih, vq1_whh, vq1_bih, vq1_bhh,
                     proj_w, proj_b, codebook, out, ws_f, ws_hist);
  hipLaunchKernelGGL(vq_finalize_kernel, dim3(1), dim3(64), 0, stream, ws_f, ws_hist, out);
}

// Round 11
// 1766.387 us; speedup vs baseline: 1.0940x; 1.0940x over previous
//
#include <hip/hip_runtime.h>
#include <math.h>
#include <stdint.h>

#define B_TOT 2048
#define SEQ   512
#define DIN   5
#define HID   64
#define EDIM  32
#define NEMB  64
#define BT    8
#define NBLK_STREAM 256
#define COMB  96
#define OUTC  (B_TOT*COMB)

typedef __attribute__((ext_vector_type(8))) _Float16 half8;  // 8 fp16 = 4 VGPRs
typedef __attribute__((ext_vector_type(4))) float float4v;

__device__ __forceinline__ float fsig(float x){ return 1.0f/(1.0f + __expf(-x)); }
__device__ __forceinline__ float ftanh(float x){
  float xc = fminf(fmaxf(x, -15.f), 15.f);
  float e  = __expf(-2.f*xc);
  return (1.f - e) / (1.f + e);
}
#define MFMA16(a,b,c) __builtin_amdgcn_mfma_f32_16x16x32_f16((a),(b),(c),0,0,0)

// Fused dual-stream, fp16. 512 blocks x 1024 thr. Compiled at the PROVEN
// spill-free budget (waves_per_eu(4,4) -> 64 VGPR, R8/R9 evidence; R10's
// (8,8) forced 32 VGPR and spilled 800 MB to scratch). 64 VGPR is the HW
// 8-waves/EU threshold, so the scheduler packs 2 blocks/CU (2048 thr, 21.5 KB
// LDS) and the two blocks' barrier phases overlap.
// blocks [0,256)=CNN, [256,512)=VQ, BT=8 batches/block (B cols 8..15 pad).
// LDS operand = 5 shared K-tiles: T0=Y/x, T1=h0[0:32), T2=h0[32:64),
// T3=h1[0:32), T4=h1[32:64). L0 reads {T0,T1,T2}; L1 reads {T1,T2,T3,T4}.
// Wave w owns M-tile w, PERMUTED rows (tile row m <-> orig row
// 64*(m&3)+4*w+(m>>2)) so D reg r = gate r of unit u=4w+quad -> act fully
// in-register; bias pre-loaded as the MFMA C operand. 2 barriers/step.
__global__ __launch_bounds__(1024)
__attribute__((amdgpu_waves_per_eu(4, 4)))
void fused_kernel(const float* __restrict__ xg,
                  const float* __restrict__ conv_w, const float* __restrict__ conv_b,
                  const float* __restrict__ bn_g, const float* __restrict__ bn_b,
                  const float* __restrict__ bn_m, const float* __restrict__ bn_v,
                  const float* __restrict__ cnn0_wih, const float* __restrict__ cnn0_whh,
                  const float* __restrict__ cnn0_bih, const float* __restrict__ cnn0_bhh,
                  const float* __restrict__ cnn1_wih, const float* __restrict__ cnn1_whh,
                  const float* __restrict__ cnn1_bih, const float* __restrict__ cnn1_bhh,
                  const float* __restrict__ vq0_wih, const float* __restrict__ vq0_whh,
                  const float* __restrict__ vq0_bih, const float* __restrict__ vq0_bhh,
                  const float* __restrict__ vq1_wih, const float* __restrict__ vq1_whh,
                  const float* __restrict__ vq1_bih, const float* __restrict__ vq1_bhh,
                  const float* __restrict__ proj_w, const float* __restrict__ proj_b,
                  const float* __restrict__ codebook,
                  float* __restrict__ out, float* __restrict__ ws_f,
                  int* __restrict__ ws_hist)
{
  __shared__ __align__(16) _Float16 ZT[5][4][16][8];   // 5 K-tiles, 16 cols (8 pad)
  __shared__ __align__(16) float hfin[BT][HID];
  __shared__ __align__(16) float pbuf[BT][EDIM];
  __shared__ float wcs[16][32];
  __shared__ float xwin[3][BT][DIN];

  const int tid  = threadIdx.x;
  const bool is_cnn = (blockIdx.x < NBLK_STREAM);
  const int b0   = (is_cnn ? blockIdx.x : blockIdx.x - NBLK_STREAM) * BT;
  const int w    = tid >> 6;      // wave = M-tile, 0..15
  const int lane = tid & 63;
  const int n16  = lane & 15;     // B/D col; batch if < 8
  const int quad = lane >> 4;
  const int u    = 4*w + quad;    // unit owned by this lane
  const bool act_lane = (n16 < BT);

  const float* wih0 = is_cnn ? cnn0_wih : vq0_wih;
  const float* whh0 = is_cnn ? cnn0_whh : vq0_whh;
  const float* bih0 = is_cnn ? cnn0_bih : vq0_bih;
  const float* bhh0 = is_cnn ? cnn0_bhh : vq0_bhh;
  const float* wih1 = is_cnn ? cnn1_wih : vq1_wih;
  const float* whh1 = is_cnn ? cnn1_whh : vq1_whh;
  const float* bih1 = is_cnn ? cnn1_bih : vq1_bih;
  const float* bhh1 = is_cnn ? cnn1_bhh : vq1_bhh;

  // ---- A-frags fp16, permuted rows. A[m=lane&15][k=quad*8+j]. 28 VGPRs.
  const int orow = 64*(n16 & 3) + 4*w + (n16 >> 2);
  half8 Ah0[3], Ah1[4];
#pragma unroll
  for (int kt = 0; kt < 3; ++kt) {
    half8 vh;
#pragma unroll
    for (int j = 0; j < 8; ++j) {
      const int g = kt*32 + quad*8 + j;
      float wv;
      if (is_cnn) wv = (g < 32) ? wih0[orow*32 + g] : whh0[orow*64 + (g-32)];
      else        wv = (g < 5) ? wih0[orow*5 + g] : (g < 32 ? 0.f : whh0[orow*64 + (g-32)]);
      vh[j] = (_Float16)wv;
    }
    Ah0[kt] = vh;
  }
#pragma unroll
  for (int kt = 0; kt < 4; ++kt) {
    half8 vh;
#pragma unroll
    for (int j = 0; j < 8; ++j) {
      const int g = kt*32 + quad*8 + j;
      float wv = (g < 64) ? wih1[orow*64 + g] : whh1[orow*64 + (g-64)];
      vh[j] = (_Float16)wv;
    }
    Ah1[kt] = vh;
  }

  // biases as MFMA C-init: reg r = gate r of unit u
  float4v bc0, bc1;
#pragma unroll
  for (int r = 0; r < 4; ++r) {
    bc0[r] = bih0[64*r + u] + bhh0[64*r + u];
    bc1[r] = bih1[64*r + u] + bhh1[64*r + u];
  }

  // zero ZT (pads + h(-1)=0): 5*4*16*8 halfwords = 1280 u32
  for (int i2 = tid; i2 < 5*4*16*8/2; i2 += 1024) ((uint32_t*)ZT)[i2] = 0;

  const int xn = tid / 5, xi = tid % 5;
  float xpref = 0.f;

  _Float16* Zb = (_Float16*)ZT;
  #define ZIDX(tile,k32,n) (((tile)*4 + (((k32)>>3)&3))*128 + (n)*8 + ((k32)&7))

  // ================= prologue =================
  if (is_cnn) {
    if (tid < 32) {
      float s = bn_g[tid] * rsqrtf(bn_v[tid] + 1e-5f);
#pragma unroll
      for (int i = 0; i < 5; ++i)
#pragma unroll
        for (int tau = 0; tau < 3; ++tau)
          wcs[tau*5 + i][tid] = conv_w[tid*15 + i*3 + tau] * s;
      wcs[15][tid] = (conv_b[tid] - bn_m[tid]) * s + bn_b[tid];
    }
    if (tid < BT*DIN) {
      xwin[0][xn][xi] = xg[((size_t)(b0+xn)*SEQ + 0)*DIN + xi];
      xwin[1][xn][xi] = xg[((size_t)(b0+xn)*SEQ + 1)*DIN + xi];
      xwin[2][xn][xi] = xg[((size_t)(b0+xn)*SEQ + 2)*DIN + xi];
    }
    __syncthreads();
    if (tid < 256) {   // conv y(0): taps x(-1)=0, x(0), x(1) -> T0
      const int cc = tid >> 3, cn = tid & 7;
      float s = wcs[15][cc];
#pragma unroll
      for (int i = 0; i < 5; ++i)
        s += wcs[5+i][cc]*xwin[0][cn][i] + wcs[10+i][cc]*xwin[1][cn][i];
      s = fmaxf(s, 0.f);
      Zb[ZIDX(0, cc, cn)] = (_Float16)s;
    }
  } else {
    if (tid < BT*DIN) {   // x(0) -> T0 k<5
      float xv = xg[((size_t)(b0+xn)*SEQ + 0)*DIN + xi];
      Zb[ZIDX(0, xi, xn)] = (_Float16)xv;
    }
  }
  __syncthreads();

  float c0 = 0.f, c1 = 0.f, h1v = 0.f;
  // MFMA G0(0)
  {
    half8 bt0 = *(const half8*)&ZT[0][quad][n16][0];
    half8 bt1 = *(const half8*)&ZT[1][quad][n16][0];
    half8 bt2 = *(const half8*)&ZT[2][quad][n16][0];
    float4v a0 = bc0;
    a0 = MFMA16(Ah0[0], bt0, a0);
    a0 = MFMA16(Ah0[1], bt1, a0);
    a0 = MFMA16(Ah0[2], bt2, a0);
    __syncthreads();   // reads done before act writes
    if (act_lane) {
      c0 = fsig(a0[1])*c0 + fsig(a0[0])*ftanh(a0[2]);
      float h0 = fsig(a0[3])*ftanh(c0);
      Zb[ZIDX(1 + (u>>5), u & 31, n16)] = (_Float16)h0;
    }
  }
  // stage y(1)/x(1), prefetch
  if (is_cnn) {
    if (tid < 256) {   // conv y(1): x(0),x(1),x(2)
      const int cc = tid >> 3, cn = tid & 7;
      float s = wcs[15][cc];
#pragma unroll
      for (int i = 0; i < 5; ++i)
        s += wcs[i][cc]*xwin[0][cn][i] + wcs[5+i][cc]*xwin[1][cn][i]
           + wcs[10+i][cc]*xwin[2][cn][i];
      s = fmaxf(s, 0.f);
      Zb[ZIDX(0, cc, cn)] = (_Float16)s;
    }
    if (tid < BT*DIN) xpref = xg[((size_t)(b0+xn)*SEQ + 3)*DIN + xi];   // x(3)
  } else {
    if (tid < BT*DIN) {    // x(1) -> T0
      float xv = xg[((size_t)(b0+xn)*SEQ + 1)*DIN + xi];
      Zb[ZIDX(0, xi, xn)] = (_Float16)xv;
      xpref = xg[((size_t)(b0+xn)*SEQ + 2)*DIN + xi];                   // x(2)
    }
  }
  __syncthreads();

  int sp = 1, scu = 2, snx = 0;   // cnn xwin slots: x(t+1), x(t+2), x(t+3)-incoming

  // ================= main loop: 2 barriers/step =================
  for (int t = 0; t < SEQ; ++t) {
    // ---- phase A: commit x(t+3) (cnn) + MFMA G1(t), G0(t+1)
    if (is_cnn && tid < BT*DIN) xwin[snx][xn][xi] = xpref;
    half8 bt0 = *(const half8*)&ZT[0][quad][n16][0];
    half8 bt1 = *(const half8*)&ZT[1][quad][n16][0];
    half8 bt2 = *(const half8*)&ZT[2][quad][n16][0];
    half8 bt3 = *(const half8*)&ZT[3][quad][n16][0];
    half8 bt4 = *(const half8*)&ZT[4][quad][n16][0];
    float4v a1 = bc1, a0 = bc0;
    a1 = MFMA16(Ah1[0], bt1, a1);
    a1 = MFMA16(Ah1[1], bt2, a1);
    a1 = MFMA16(Ah1[2], bt3, a1);
    a1 = MFMA16(Ah1[3], bt4, a1);
    a0 = MFMA16(Ah0[0], bt0, a0);
    a0 = MFMA16(Ah0[1], bt1, a0);
    a0 = MFMA16(Ah0[2], bt2, a0);
    __syncthreads();  // A -> B (all Z reads complete)

    // ---- phase B: in-register acts + Z writes + conv/x staging
    if (act_lane) {
      {  // L1 act(t)
        c1 = fsig(a1[1])*c1 + fsig(a1[0])*ftanh(a1[2]);
        float h1 = fsig(a1[3])*ftanh(c1);
        Zb[ZIDX(3 + (u>>5), u & 31, n16)] = (_Float16)h1;
        if (is_cnn) h1v = h1;
        else if (t == SEQ-1) hfin[n16][u] = h1;
      }
      {  // L0 act(t+1)
        c0 = fsig(a0[1])*c0 + fsig(a0[0])*ftanh(a0[2]);
        float h0 = fsig(a0[3])*ftanh(c0);
        Zb[ZIDX(1 + (u>>5), u & 31, n16)] = (_Float16)h0;
      }
    }
    if (is_cnn) {      // conv y(t+2): x(t+1),x(t+2),x(t+3)
      if (tid < 256) {
        const int cc = tid >> 3, cn = tid & 7;
        float s = wcs[15][cc];
#pragma unroll
        for (int i = 0; i < 5; ++i)
          s += wcs[i][cc]*xwin[sp][cn][i] + wcs[5+i][cc]*xwin[scu][cn][i]
             + wcs[10+i][cc]*xwin[snx][cn][i];
        s = fmaxf(s, 0.f);
        Zb[ZIDX(0, cc, cn)] = (_Float16)s;
      }
      if (tid < BT*DIN) {
        const int tq = t + 4;
        xpref = (tq < SEQ) ? xg[((size_t)(b0+xn)*SEQ + tq)*DIN + xi] : 0.f;
      }
    } else {
      if (tid < BT*DIN) {  // x(t+2) -> T0
        Zb[ZIDX(0, xi, xn)] = (_Float16)xpref;
        const int tq = t + 3;
        xpref = (tq < SEQ) ? xg[((size_t)(b0+xn)*SEQ + tq)*DIN + xi] : 0.f;
      }
    }
    { int tmp = sp; sp = scu; scu = snx; snx = tmp; }
    __syncthreads();  // B -> A(t+1)
  }

  // ================= epilogue =================
  if (is_cnn) {
    if (act_lane) {
      const size_t gb = (size_t)(b0 + n16);
      out[gb*COMB + u]        = h1v;
      out[OUTC + gb*COMB + u] = h1v;
    }
  } else {
    if (tid < 256) {  // projection: vq_proj[8][32]
      const int pn = tid >> 5, pe = tid & 31;
      float s = proj_b[pe];
      const float* pw = proj_w + pe*HID;
#pragma unroll
      for (int k = 0; k < HID; ++k) s += hfin[pn][k] * pw[k];
      pbuf[pn][pe] = s;
    }
    __syncthreads();
    // argmin: wave w handles batch w (w<8), lane = code idx
    if (w < BT) {
      const int bb = w;
      const int nn = lane;
      const float* cbn = codebook + nn*EDIM;
      float d = 0.f;
#pragma unroll
      for (int k = 0; k < EDIM; ++k) { float df = pbuf[bb][k] - cbn[k]; d += df*df; }
      int bi = nn;
#pragma unroll
      for (int off = 32; off > 0; off >>= 1) {
        float od = __shfl_down(d, off, 64);
        int   oi = __shfl_down(bi, off, 64);
        if (od < d || (od == d && oi < bi)) { d = od; bi = oi; }
      }
      bi = __shfl(bi, 0, 64);
      float lv = 0.f;
      if (nn < EDIM) {
        float q = codebook[bi*EDIM + nn];
        const size_t gb = (size_t)(b0 + bb);
        out[gb*COMB + HID + nn]        = q;
        out[OUTC + gb*COMB + HID + nn] = q;
        float df = q - pbuf[bb][nn];
        lv = df*df;
      }
#pragma unroll
      for (int off = 32; off > 0; off >>= 1) lv += __shfl_down(lv, off, 64);
      if (nn == 0) { atomicAdd(ws_f, lv); atomicAdd(&ws_hist[bi], 1); }
    }
  }
}

// ===================== scalars =====================
__global__ void zero_ws_kernel(float* ws_f, int* ws_hist) {
  const int t = threadIdx.x;
  if (t == 0) ws_f[0] = 0.f;
  if (t < NEMB) ws_hist[t] = 0;
}

__global__ void vq_finalize_kernel(const float* __restrict__ ws_f,
                                   const int* __restrict__ ws_hist,
                                   float* __restrict__ out) {
  const int t = threadIdx.x;  // 64 threads = 1 wave
  float p = (float)ws_hist[t] * (1.0f / (float)B_TOT);
  float e = -p * logf(p + 1e-10f);
#pragma unroll
  for (int off = 32; off > 0; off >>= 1) e += __shfl_down(e, off, 64);
  if (t == 0) {
    float mse = ws_f[0] * (1.0f / (float)(B_TOT * EDIM));
    out[2*OUTC + 0] = mse * 1.01f;   // q_loss + 0.01*e_loss (identical fwd)
    out[2*OUTC + 1] = expf(e);       // perplexity
  }
}

extern "C" void kernel_launch(void* const* d_in, const int* in_sizes, int n_in,
                              void* d_out, int out_size, void* d_ws, size_t ws_size,
                              hipStream_t stream) {
  const float* x        = (const float*)d_in[0];
  const float* conv_w   = (const float*)d_in[1];
  const float* conv_b   = (const float*)d_in[2];
  const float* bn_g     = (const float*)d_in[3];
  const float* bn_b     = (const float*)d_in[4];
  const float* bn_m     = (const float*)d_in[5];
  const float* bn_v     = (const float*)d_in[6];
  const float* cnn0_wih = (const float*)d_in[7];
  const float* cnn0_whh = (const float*)d_in[8];
  const float* cnn0_bih = (const float*)d_in[9];
  const float* cnn0_bhh = (const float*)d_in[10];
  const float* cnn1_wih = (const float*)d_in[11];
  const float* cnn1_whh = (const float*)d_in[12];
  const float* cnn1_bih = (const float*)d_in[13];
  const float* cnn1_bhh = (const float*)d_in[14];
  const float* vq0_wih  = (const float*)d_in[15];
  const float* vq0_whh  = (const float*)d_in[16];
  const float* vq0_bih  = (const float*)d_in[17];
  const float* vq0_bhh  = (const float*)d_in[18];
  const float* vq1_wih  = (const float*)d_in[19];
  const float* vq1_whh  = (const float*)d_in[20];
  const float* vq1_bih  = (const float*)d_in[21];
  const float* vq1_bhh  = (const float*)d_in[22];
  const float* proj_w   = (const float*)d_in[23];
  const float* proj_b   = (const float*)d_in[24];
  const float* codebook = (const float*)d_in[25];

  float* out     = (float*)d_out;
  float* ws_f    = (float*)d_ws;
  int*   ws_hist = (int*)d_ws + 16;

  hipLaunchKernelGGL(zero_ws_kernel, dim3(1), dim3(64), 0, stream, ws_f, ws_hist);
  hipLaunchKernelGGL(fused_kernel, dim3(2*NBLK_STREAM), dim3(1024), 0, stream,
                     x, conv_w, conv_b, bn_g, bn_b, bn_m, bn_v,
                     cnn0_wih, cnn0_whh, cnn0_bih, cnn0_bhh,
                     cnn1_wih, cnn1_whh, cnn1_bih, cnn1_bhh,
                     vq0_wih, vq0_whh, vq0_bih, vq0_bhh,
                     vq1_wih, vq1_whh, vq1_bih, vq1_bhh,
                     proj_w, proj_b, codebook, out, ws_f, ws_hist);
  hipLaunchKernelGGL(vq_finalize_kernel, dim3(1), dim3(64), 0, stream, ws_f, ws_hist, out);
}

// Round 12
// 927.658 us; speedup vs baseline: 2.0831x; 1.9041x over previous
//
#include <hip/hip_runtime.h>
#include <math.h>
#include <stdint.h>

#define B_TOT 2048
#define SEQ   512
#define DIN   5
#define HID   64
#define EDIM  32
#define NEMB  64
#define BT    16
#define NBLK_STREAM 128
#define COMB  96
#define OUTC  (B_TOT*COMB)

typedef __attribute__((ext_vector_type(8))) _Float16 half8;  // 8 fp16 = 4 VGPRs
typedef __attribute__((ext_vector_type(4))) float float4v;

__device__ __forceinline__ float fsig(float x){ return 1.0f/(1.0f + __expf(-x)); }
__device__ __forceinline__ float ftanh(float x){
  float xc = fminf(fmaxf(x, -15.f), 15.f);
  float e  = __expf(-2.f*xc);
  return (1.f - e) / (1.f + e);
}
#define MFMA16(a,b,c) __builtin_amdgcn_mfma_f32_16x16x32_f16((a),(b),(c),0,0,0)

// Fused dual-stream, fp16, DOUBLE-BUFFERED Z -> 1 barrier/step.
// 256 blocks x 1024 thr (R8's proven spill-free shape: VGPR=64, waves_per_eu
// (4,4); R10/R11 showed the attribute couples budget+residency, so we stay at
// 1 block/CU and cut barrier count instead).
// blocks [0,128)=CNN, [128,256)=VQ, BT=16 batches/block.
// Z buf = 5 K-tiles: T0=Y/x, T1=h0[0:32), T2=h0[32:64), T3=h1[0:32),
// T4=h1[32:64). Step t: MFMA reads buf[t&1] (G1(t): T1-T4; G0(t+1): T0-T2),
// act/conv write buf[1-(t&1)] (h1(t)->T3/4, h0(t+1)->T1/2, y(t+2)->T0).
// Disjoint buffers -> no read/write barrier; one barrier/step (write->read).
// Wave w owns M-tile w, PERMUTED rows (tile row m <-> orig row
// 64*(m&3)+4*w+(m>>2)) so D reg r = gate r of unit u=4w+quad; act in-register;
// bias preloaded as MFMA C. cnn x-window = 4-slot ring (slot written in an
// interval is never read in that interval).
__global__ __launch_bounds__(1024)
__attribute__((amdgpu_waves_per_eu(4, 4)))
void fused_kernel(const float* __restrict__ xg,
                  const float* __restrict__ conv_w, const float* __restrict__ conv_b,
                  const float* __restrict__ bn_g, const float* __restrict__ bn_b,
                  const float* __restrict__ bn_m, const float* __restrict__ bn_v,
                  const float* __restrict__ cnn0_wih, const float* __restrict__ cnn0_whh,
                  const float* __restrict__ cnn0_bih, const float* __restrict__ cnn0_bhh,
                  const float* __restrict__ cnn1_wih, const float* __restrict__ cnn1_whh,
                  const float* __restrict__ cnn1_bih, const float* __restrict__ cnn1_bhh,
                  const float* __restrict__ vq0_wih, const float* __restrict__ vq0_whh,
                  const float* __restrict__ vq0_bih, const float* __restrict__ vq0_bhh,
                  const float* __restrict__ vq1_wih, const float* __restrict__ vq1_whh,
                  const float* __restrict__ vq1_bih, const float* __restrict__ vq1_bhh,
                  const float* __restrict__ proj_w, const float* __restrict__ proj_b,
                  const float* __restrict__ codebook,
                  float* __restrict__ out, float* __restrict__ ws_f,
                  int* __restrict__ ws_hist)
{
  __shared__ __align__(16) _Float16 ZT[2][5][4][BT][8];  // 2 bufs x 5 K-tiles
  __shared__ __align__(16) float hfin[BT][HID];
  __shared__ __align__(16) float pbuf[BT][EDIM];
  __shared__ float wcs[16][32];
  __shared__ float xwin[4][BT][DIN];                      // 4-slot ring

  const int tid  = threadIdx.x;
  const bool is_cnn = (blockIdx.x < NBLK_STREAM);
  const int b0   = (is_cnn ? blockIdx.x : blockIdx.x - NBLK_STREAM) * BT;
  const int w    = tid >> 6;      // wave = M-tile, 0..15
  const int lane = tid & 63;
  const int n16  = lane & 15;     // batch (B/D col)
  const int quad = lane >> 4;
  const int u    = 4*w + quad;    // unit owned by this lane

  const float* wih0 = is_cnn ? cnn0_wih : vq0_wih;
  const float* whh0 = is_cnn ? cnn0_whh : vq0_whh;
  const float* bih0 = is_cnn ? cnn0_bih : vq0_bih;
  const float* bhh0 = is_cnn ? cnn0_bhh : vq0_bhh;
  const float* wih1 = is_cnn ? cnn1_wih : vq1_wih;
  const float* whh1 = is_cnn ? cnn1_whh : vq1_whh;
  const float* bih1 = is_cnn ? cnn1_bih : vq1_bih;
  const float* bhh1 = is_cnn ? cnn1_bhh : vq1_bhh;

  // ---- A-frags fp16, permuted rows. A[m=lane&15][k=quad*8+j]. 28 VGPRs.
  const int orow = 64*(n16 & 3) + 4*w + (n16 >> 2);
  half8 Ah0[3], Ah1[4];
#pragma unroll
  for (int kt = 0; kt < 3; ++kt) {
    half8 vh;
#pragma unroll
    for (int j = 0; j < 8; ++j) {
      const int g = kt*32 + quad*8 + j;
      float wv;
      if (is_cnn) wv = (g < 32) ? wih0[orow*32 + g] : whh0[orow*64 + (g-32)];
      else        wv = (g < 5) ? wih0[orow*5 + g] : (g < 32 ? 0.f : whh0[orow*64 + (g-32)]);
      vh[j] = (_Float16)wv;
    }
    Ah0[kt] = vh;
  }
#pragma unroll
  for (int kt = 0; kt < 4; ++kt) {
    half8 vh;
#pragma unroll
    for (int j = 0; j < 8; ++j) {
      const int g = kt*32 + quad*8 + j;
      float wv = (g < 64) ? wih1[orow*64 + g] : whh1[orow*64 + (g-64)];
      vh[j] = (_Float16)wv;
    }
    Ah1[kt] = vh;
  }

  // biases as MFMA C-init: reg r = gate r of unit u
  float4v bc0, bc1;
#pragma unroll
  for (int r = 0; r < 4; ++r) {
    bc0[r] = bih0[64*r + u] + bhh0[64*r + u];
    bc1[r] = bih1[64*r + u] + bhh1[64*r + u];
  }

  // zero both Z buffers (pads + h(-1)=0): 2*5*4*16*8 hw = 2560 u32
  for (int i2 = tid; i2 < 2*5*4*BT*8/2; i2 += 1024) ((uint32_t*)ZT)[i2] = 0;

  const int xn = tid / 5, xi = tid % 5;
  float xpref = 0.f;

  #define ZB(b) ((_Float16*)(&ZT[(b)][0][0][0][0]))
  #define ZIDX(tile,k32,n) (((tile)*4 + (((k32)>>3)&3))*(BT*8) + (n)*8 + ((k32)&7))

  // ================= prologue =================
  if (is_cnn) {
    if (tid < 32) {
      float s = bn_g[tid] * rsqrtf(bn_v[tid] + 1e-5f);
#pragma unroll
      for (int i = 0; i < 5; ++i)
#pragma unroll
        for (int tau = 0; tau < 3; ++tau)
          wcs[tau*5 + i][tid] = conv_w[tid*15 + i*3 + tau] * s;
      wcs[15][tid] = (conv_b[tid] - bn_m[tid]) * s + bn_b[tid];
    }
    if (tid < BT*DIN) {   // x(0..3) -> slots 0..3
#pragma unroll
      for (int j = 0; j < 4; ++j)
        xwin[j][xn][xi] = xg[((size_t)(b0+xn)*SEQ + j)*DIN + xi];
    }
    __syncthreads();
    if (tid < 512) {   // conv y(0): taps x(-1)=0, x(0), x(1) -> buf1.T0
      const int cc = tid >> 4, cn = tid & 15;
      float s = wcs[15][cc];
#pragma unroll
      for (int i = 0; i < 5; ++i)
        s += wcs[5+i][cc]*xwin[0][cn][i] + wcs[10+i][cc]*xwin[1][cn][i];
      s = fmaxf(s, 0.f);
      ZB(1)[ZIDX(0, cc, cn)] = (_Float16)s;
    }
  } else {
    if (tid < BT*DIN) {   // x(0) -> buf1.T0
      float xv = xg[((size_t)(b0+xn)*SEQ + 0)*DIN + xi];
      ZB(1)[ZIDX(0, xi, xn)] = (_Float16)xv;
    }
  }
  __syncthreads();

  float c0 = 0.f, c1 = 0.f, h1v = 0.f;
  // MFMA G0(0) reading buf1 (T1/T2 zero = h0(-1))
  {
    half8 bt0 = *(const half8*)&ZT[1][0][quad][n16][0];
    half8 bt1 = *(const half8*)&ZT[1][1][quad][n16][0];
    half8 bt2 = *(const half8*)&ZT[1][2][quad][n16][0];
    float4v a0 = bc0;
    a0 = MFMA16(Ah0[0], bt0, a0);
    a0 = MFMA16(Ah0[1], bt1, a0);
    a0 = MFMA16(Ah0[2], bt2, a0);
    // act L0(0) -> h0(0) into buf0.T1/T2
    c0 = fsig(a0[1])*c0 + fsig(a0[0])*ftanh(a0[2]);
    float h0 = fsig(a0[3])*ftanh(c0);
    ZB(0)[ZIDX(1 + (u>>5), u & 31, n16)] = (_Float16)h0;
  }
  // stage y(1)/x(1) into buf0.T0; buf0.T3/T4 stay zero (h1(-1))
  if (is_cnn) {
    if (tid < 512) {   // conv y(1): x(0),x(1),x(2)
      const int cc = tid >> 4, cn = tid & 15;
      float s = wcs[15][cc];
#pragma unroll
      for (int i = 0; i < 5; ++i)
        s += wcs[i][cc]*xwin[0][cn][i] + wcs[5+i][cc]*xwin[1][cn][i]
           + wcs[10+i][cc]*xwin[2][cn][i];
      s = fmaxf(s, 0.f);
      ZB(0)[ZIDX(0, cc, cn)] = (_Float16)s;
    }
    if (tid < BT*DIN) xpref = xg[((size_t)(b0+xn)*SEQ + 4)*DIN + xi];   // x(4)
  } else {
    if (tid < BT*DIN) {    // x(1) -> buf0.T0
      float xv = xg[((size_t)(b0+xn)*SEQ + 1)*DIN + xi];
      ZB(0)[ZIDX(0, xi, xn)] = (_Float16)xv;
      xpref = xg[((size_t)(b0+xn)*SEQ + 2)*DIN + xi];                   // x(2)
    }
  }
  __syncthreads();

  // ================= main loop: 1 barrier/step =================
  for (int t = 0; t < SEQ; ++t) {
    const int rb = t & 1, wr = rb ^ 1;
    // ---- MFMA G1(t), G0(t+1) from buf[rb]
    half8 bt0 = *(const half8*)&ZT[rb][0][quad][n16][0];
    half8 bt1 = *(const half8*)&ZT[rb][1][quad][n16][0];
    half8 bt2 = *(const half8*)&ZT[rb][2][quad][n16][0];
    half8 bt3 = *(const half8*)&ZT[rb][3][quad][n16][0];
    half8 bt4 = *(const half8*)&ZT[rb][4][quad][n16][0];
    float4v a1 = bc1, a0 = bc0;
    a1 = MFMA16(Ah1[0], bt1, a1);
    a1 = MFMA16(Ah1[1], bt2, a1);
    a1 = MFMA16(Ah1[2], bt3, a1);
    a1 = MFMA16(Ah1[3], bt4, a1);
    a0 = MFMA16(Ah0[0], bt0, a0);
    a0 = MFMA16(Ah0[1], bt1, a0);
    a0 = MFMA16(Ah0[2], bt2, a0);

    // ---- acts (in-register) + writes into buf[wr]
    {  // L1 act(t)
      c1 = fsig(a1[1])*c1 + fsig(a1[0])*ftanh(a1[2]);
      float h1 = fsig(a1[3])*ftanh(c1);
      ZB(wr)[ZIDX(3 + (u>>5), u & 31, n16)] = (_Float16)h1;
      if (is_cnn) h1v = h1;
      else if (t == SEQ-1) hfin[n16][u] = h1;
    }
    {  // L0 act(t+1)
      c0 = fsig(a0[1])*c0 + fsig(a0[0])*ftanh(a0[2]);
      float h0 = fsig(a0[3])*ftanh(c0);
      ZB(wr)[ZIDX(1 + (u>>5), u & 31, n16)] = (_Float16)h0;
    }
    if (is_cnn) {      // conv y(t+2): x(t+1),x(t+2),x(t+3) -> buf[wr].T0
      if (tid < 512) {
        const int cc = tid >> 4, cn = tid & 15;
        const int s1 = (t+1)&3, s2 = (t+2)&3, s3 = (t+3)&3;
        float s = wcs[15][cc];
#pragma unroll
        for (int i = 0; i < 5; ++i)
          s += wcs[i][cc]*xwin[s1][cn][i] + wcs[5+i][cc]*xwin[s2][cn][i]
             + wcs[10+i][cc]*xwin[s3][cn][i];
        s = fmaxf(s, 0.f);
        ZB(wr)[ZIDX(0, cc, cn)] = (_Float16)s;
      }
      if (tid < BT*DIN) {
        xwin[t & 3][xn][xi] = xpref;           // commit x(t+4) (slot not read this step)
        const int tq = t + 5;
        xpref = (tq < SEQ) ? xg[((size_t)(b0+xn)*SEQ + tq)*DIN + xi] : 0.f;
      }
    } else {
      if (tid < BT*DIN) {  // x(t+2) -> buf[wr].T0
        ZB(wr)[ZIDX(0, xi, xn)] = (_Float16)xpref;
        const int tq = t + 3;
        xpref = (tq < SEQ) ? xg[((size_t)(b0+xn)*SEQ + tq)*DIN + xi] : 0.f;
      }
    }
    __syncthreads();  // single barrier: buf[wr] writes -> next step's reads
  }

  // ================= epilogue =================
  if (is_cnn) {
    const size_t gb = (size_t)(b0 + n16);
    out[gb*COMB + u]        = h1v;
    out[OUTC + gb*COMB + u] = h1v;
  } else {
    if (tid < 512) {  // projection: vq_proj[16][32]
      const int pn = tid >> 5, pe = tid & 31;
      float s = proj_b[pe];
      const float* pw = proj_w + pe*HID;
#pragma unroll
      for (int k = 0; k < HID; ++k) s += hfin[pn][k] * pw[k];
      pbuf[pn][pe] = s;
    }
    __syncthreads();
    // argmin: wave w handles batch w (16 waves = 16 batches), lane = code idx
    {
      const int bb = w;
      const int nn = lane;
      const float* cbn = codebook + nn*EDIM;
      float d = 0.f;
#pragma unroll
      for (int k = 0; k < EDIM; ++k) { float df = pbuf[bb][k] - cbn[k]; d += df*df; }
      int bi = nn;
#pragma unroll
      for (int off = 32; off > 0; off >>= 1) {
        float od = __shfl_down(d, off, 64);
        int   oi = __shfl_down(bi, off, 64);
        if (od < d || (od == d && oi < bi)) { d = od; bi = oi; }
      }
      bi = __shfl(bi, 0, 64);
      float lv = 0.f;
      if (nn < EDIM) {
        float q = codebook[bi*EDIM + nn];
        const size_t gb = (size_t)(b0 + bb);
        out[gb*COMB + HID + nn]        = q;
        out[OUTC + gb*COMB + HID + nn] = q;
        float df = q - pbuf[bb][nn];
        lv = df*df;
      }
#pragma unroll
      for (int off = 32; off > 0; off >>= 1) lv += __shfl_down(lv, off, 64);
      if (nn == 0) { atomicAdd(ws_f, lv); atomicAdd(&ws_hist[bi], 1); }
    }
  }
}

// ===================== scalars =====================
__global__ void zero_ws_kernel(float* ws_f, int* ws_hist) {
  const int t = threadIdx.x;
  if (t == 0) ws_f[0] = 0.f;
  if (t < NEMB) ws_hist[t] = 0;
}

__global__ void vq_finalize_kernel(const float* __restrict__ ws_f,
                                   const int* __restrict__ ws_hist,
                                   float* __restrict__ out) {
  const int t = threadIdx.x;  // 64 threads = 1 wave
  float p = (float)ws_hist[t] * (1.0f / (float)B_TOT);
  float e = -p * logf(p + 1e-10f);
#pragma unroll
  for (int off = 32; off > 0; off >>= 1) e += __shfl_down(e, off, 64);
  if (t == 0) {
    float mse = ws_f[0] * (1.0f / (float)(B_TOT * EDIM));
    out[2*OUTC + 0] = mse * 1.01f;   // q_loss + 0.01*e_loss (identical fwd)
    out[2*OUTC + 1] = expf(e);       // perplexity
  }
}

extern "C" void kernel_launch(void* const* d_in, const int* in_sizes, int n_in,
                              void* d_out, int out_size, void* d_ws, size_t ws_size,
                              hipStream_t stream) {
  const float* x        = (const float*)d_in[0];
  const float* conv_w   = (const float*)d_in[1];
  const float* conv_b   = (const float*)d_in[2];
  const float* bn_g     = (const float*)d_in[3];
  const float* bn_b     = (const float*)d_in[4];
  const float* bn_m     = (const float*)d_in[5];
  const float* bn_v     = (const float*)d_in[6];
  const float* cnn0_wih = (const float*)d_in[7];
  const float* cnn0_whh = (const float*)d_in[8];
  const float* cnn0_bih = (const float*)d_in[9];
  const float* cnn0_bhh = (const float*)d_in[10];
  const float* cnn1_wih = (const float*)d_in[11];
  const float* cnn1_whh = (const float*)d_in[12];
  const float* cnn1_bih = (const float*)d_in[13];
  const float* cnn1_bhh = (const float*)d_in[14];
  const float* vq0_wih  = (const float*)d_in[15];
  const float* vq0_whh  = (const float*)d_in[16];
  const float* vq0_bih  = (const float*)d_in[17];
  const float* vq0_bhh  = (const float*)d_in[18];
  const float* vq1_wih  = (const float*)d_in[19];
  const float* vq1_whh  = (const float*)d_in[20];
  const float* vq1_bih  = (const float*)d_in[21];
  const float* vq1_bhh  = (const float*)d_in[22];
  const float* proj_w   = (const float*)d_in[23];
  const float* proj_b   = (const float*)d_in[24];
  const float* codebook = (const float*)d_in[25];

  float* out     = (float*)d_out;
  float* ws_f    = (float*)d_ws;
  int*   ws_hist = (int*)d_ws + 16;

  hipLaunchKernelGGL(zero_ws_kernel, dim3(1), dim3(64), 0, stream, ws_f, ws_hist);
  hipLaunchKernelGGL(fused_kernel, dim3(2*NBLK_STREAM), dim3(1024), 0, stream,
                     x, conv_w, conv_b, bn_g, bn_b, bn_m, bn_v,
                     cnn0_wih, cnn0_whh, cnn0_bih, cnn0_bhh,
                     cnn1_wih, cnn1_whh, cnn1_bih, cnn1_bhh,
                     vq0_wih, vq0_whh, vq0_bih, vq0_bhh,
                     vq1_wih, vq1_whh, vq1_bih, vq1_bhh,
                     proj_w, proj_b, codebook, out, ws_f, ws_hist);
  hipLaunchKernelGGL(vq_finalize_kernel, dim3(1), dim3(64), 0, stream, ws_f, ws_hist, out);
}